// Round 1
// baseline (2768.800 us; speedup 1.0000x reference)
//
#include <hip/hip_runtime.h>
#include <cstdint>
#include <cstddef>

namespace {

constexpr int Bb = 1024;
constexpr int Tt = 128;
constexpr int Ll = 16;
constexpr int Hh = 512;
constexpr int Dd = 64;
constexpr int Gg = 2048;   // 4*H
constexpr int CH = 16;     // proj chunk (timesteps)

typedef _Float16 half8 __attribute__((ext_vector_type(8)));
typedef float f32x4 __attribute__((ext_vector_type(4)));

__device__ __forceinline__ float sigm(float x) { return 1.f / (1.f + __expf(-x)); }
__device__ __forceinline__ float tanh_f(float x) { return 2.f / (1.f + __expf(-2.f * x)) - 1.f; }

// async global->LDS, 16B per lane. LDS dest must be linear in lane order.
__device__ __forceinline__ void gload16(const void* g, void* l) {
  __builtin_amdgcn_global_load_lds(
      (const __attribute__((address_space(1))) void*)g,
      (__attribute__((address_space(3))) void*)l, 16, 0, 0);
}

// ---------------- prep kernels ----------------
__global__ void k_wcat(const float* __restrict__ Wih, const float* __restrict__ Whh,
                       _Float16* __restrict__ Wcat) {
  int idx = blockIdx.x * 256 + threadIdx.x;       // n*1024 + k
  int n = idx >> 10, k = idx & 1023;
  float v = (k < Hh) ? Wih[n * Hh + k] : Whh[n * Hh + (k - Hh)];
  Wcat[idx] = (_Float16)v;
}

__global__ void k_cvt(const float* __restrict__ src, _Float16* __restrict__ dst, int n) {
  int idx = blockIdx.x * 256 + threadIdx.x;
  if (idx < n) dst[idx] = (_Float16)src[idx];
}

__global__ void k_gbias(const float* __restrict__ a, const float* __restrict__ b,
                        float* __restrict__ o) {
  int i = blockIdx.x * 256 + threadIdx.x;
  if (i < Gg) o[i] = a[i] + b[i];
}

// x1 = relu(labels @ W1^T + b1), K=16 so plain VALU
__global__ void k_label1(const float* __restrict__ labels, const float* __restrict__ W1,
                         const float* __restrict__ b1, _Float16* __restrict__ x1) {
  int idx = blockIdx.x * 256 + threadIdx.x;       // b*512 + n
  int b = idx >> 9, n = idx & 511;
  const float* lab = labels + b * Ll;
  const float* w = W1 + n * Ll;
  float s = b1[n];
#pragma unroll
  for (int l = 0; l < Ll; ++l) s += lab[l] * w[l];
  x1[idx] = (_Float16)fmaxf(s, 0.f);
}

// c = 0, h-half of A = 0, z-half of A = f16(conds + z[0])
__global__ void k_init(float* __restrict__ c, _Float16* __restrict__ A0,
                       const float* __restrict__ conds, const float* __restrict__ z0) {
  int idx = blockIdx.x * 256 + threadIdx.x;       // b*512 + h
  int b = idx >> 9, h = idx & 511;
  c[idx] = 0.f;
  A0[(size_t)b * 1024 + 512 + h] = (_Float16)0.f;
  A0[(size_t)b * 1024 + h] = (_Float16)(conds[idx] + z0[idx]);
}

// ---------------- generic TN GEMM: C[M,N] = A[M,K] @ W[N,K]^T (+bias)(+relu) ----------------
// grid = (M/BM, N/BN), 256 threads, 4 waves in 2x2. BK=64 halves.
// XOR chunk swizzle: LDS slot (row, c) holds global chunk c^(row&7); reads re-apply.
template <int BM, int BN>
__global__ __launch_bounds__(256) void gemm_tn(
    const _Float16* __restrict__ A, int lda,
    const _Float16* __restrict__ W, int ldb,
    const float* __restrict__ bias,
    float* __restrict__ Cf, _Float16* __restrict__ Ch, int ldc,
    int K, int relu, int out_mode, int t0) {
  constexpr int BK = 64;
  __shared__ __align__(16) _Float16 lA[BM * BK];
  __shared__ __align__(16) _Float16 lB[BN * BK];
  constexpr int WM = BM / 2, WN = BN / 2;
  constexpr int MF = WM / 16, NF = WN / 16;
  const int tid = threadIdx.x;
  const int lane = tid & 63;
  const int wid = tid >> 6;
  const int wm = wid >> 1, wn = wid & 1;
  const long bm0 = (long)blockIdx.x * BM, bn0 = (long)blockIdx.y * BN;
  const int srow = tid >> 3, schunk = tid & 7;

  f32x4 zero4 = {0.f, 0.f, 0.f, 0.f};
  f32x4 acc[MF][NF];
#pragma unroll
  for (int i = 0; i < MF; ++i)
#pragma unroll
    for (int j = 0; j < NF; ++j) acc[i][j] = zero4;

  for (int k0 = 0; k0 < K; k0 += BK) {
#pragma unroll
    for (int i = 0; i < BM / 32; ++i) {
      int row = i * 32 + srow;
      int gc = schunk ^ (row & 7);
      gload16(A + (bm0 + row) * lda + k0 + gc * 8, &lA[row * BK + schunk * 8]);
    }
#pragma unroll
    for (int i = 0; i < BN / 32; ++i) {
      int row = i * 32 + srow;
      int gc = schunk ^ (row & 7);
      gload16(W + (bn0 + row) * ldb + k0 + gc * 8, &lB[row * BK + schunk * 8]);
    }
    __syncthreads();
#pragma unroll
    for (int kk = 0; kk < BK; kk += 32) {
      half8 af[MF], bf[NF];
#pragma unroll
      for (int mi = 0; mi < MF; ++mi) {
        int r = wm * WM + mi * 16 + (lane & 15);
        int c = (kk >> 3) + (lane >> 4);
        af[mi] = *(const half8*)&lA[r * BK + ((c ^ (r & 7)) << 3)];
      }
#pragma unroll
      for (int ni = 0; ni < NF; ++ni) {
        int r = wn * WN + ni * 16 + (lane & 15);
        int c = (kk >> 3) + (lane >> 4);
        bf[ni] = *(const half8*)&lB[r * BK + ((c ^ (r & 7)) << 3)];
      }
#pragma unroll
      for (int mi = 0; mi < MF; ++mi)
#pragma unroll
        for (int ni = 0; ni < NF; ++ni)
          acc[mi][ni] = __builtin_amdgcn_mfma_f32_16x16x32_f16(af[mi], bf[ni], acc[mi][ni], 0, 0, 0);
    }
    __syncthreads();
  }

  // epilogue. C/D layout: col = lane&15, row = (lane>>4)*4 + j
#pragma unroll
  for (int mi = 0; mi < MF; ++mi) {
#pragma unroll
    for (int ni = 0; ni < NF; ++ni) {
      long col = bn0 + wn * WN + ni * 16 + (lane & 15);
      float bv = bias ? bias[col] : 0.f;
#pragma unroll
      for (int j = 0; j < 4; ++j) {
        long grow = bm0 + wm * WM + mi * 16 + (lane >> 4) * 4 + j;
        float v = acc[mi][ni][j] + bv;
        if (relu) v = fmaxf(v, 0.f);
        if (Ch) {
          Ch[grow * ldc + col] = (_Float16)v;
        } else {
          // out_mode 1: rows are tl*1024 + b of a CH-chunk; scatter into out[b][t0+tl][d]
          long off = out_mode ? (((grow & 1023) * Tt + t0 + (grow >> 10)) * Dd + col)
                              : (grow * ldc + col);
          Cf[off] = v;
        }
      }
    }
  }
}

// ---------------- fused recurrent step ----------------
// gates = Acur @ Wcat^T (+gbias), LSTM pointwise fused in epilogue.
// Block: 64 batch rows x 16 h-cols (x all 4 gate strips). 256 thr = 4 waves,
// wave w owns rows w*16..w*16+15; frag ni == gate ni, so each lane holds
// i,f,g,o for its (b,h) in registers. Writes h (f16) into Anext h-half and
// hchunk, next inp = f16(conds+z[t+1]) into Anext z-half. Ping-pong A buffers
// make the in-kernel write race-free vs other blocks still reading Acur.
__global__ __launch_bounds__(256) void step_fused(
    const _Float16* __restrict__ Acur,   // [1024][1024] = [inp | h]
    const _Float16* __restrict__ Wcat,   // [2048][1024]
    const float* __restrict__ gbias,     // [2048]
    float* __restrict__ c,               // [1024][512]
    _Float16* __restrict__ Anext,        // [1024][1024]
    _Float16* __restrict__ hchunk,       // [CH][1024][512]
    const float* __restrict__ conds,     // [1024][512]
    const float* __restrict__ znext,     // [1024][512] or null (last step)
    int tloc) {
  constexpr int BK = 64;
  __shared__ __align__(16) _Float16 lA[64 * BK];
  __shared__ __align__(16) _Float16 lB[64 * BK];
  const int tid = threadIdx.x;
  const int lane = tid & 63;
  const int w = tid >> 6;                 // wave id -> row group
  const long bm0 = (long)blockIdx.x * 64;
  const int hc0 = blockIdx.y * 16;
  const int srow = tid >> 3, schunk = tid & 7;

  f32x4 zero4 = {0.f, 0.f, 0.f, 0.f};
  f32x4 acc[4];
#pragma unroll
  for (int i = 0; i < 4; ++i) acc[i] = zero4;

  for (int k0 = 0; k0 < 1024; k0 += BK) {
#pragma unroll
    for (int i = 0; i < 2; ++i) {
      int row = i * 32 + srow;
      int gc = schunk ^ (row & 7);
      gload16(Acur + (bm0 + row) * 1024 + k0 + gc * 8, &lA[row * BK + schunk * 8]);
    }
#pragma unroll
    for (int i = 0; i < 2; ++i) {
      int rb = i * 32 + srow;                       // tile row: strip = rb>>4, col = rb&15
      long grow = ((long)(rb >> 4) << 9) + hc0 + (rb & 15);
      int gc = schunk ^ (rb & 7);
      gload16(Wcat + grow * 1024 + k0 + gc * 8, &lB[rb * BK + schunk * 8]);
    }
    __syncthreads();
#pragma unroll
    for (int kk = 0; kk < BK; kk += 32) {
      int cch = (kk >> 3) + (lane >> 4);
      int ra = w * 16 + (lane & 15);
      half8 af = *(const half8*)&lA[ra * BK + (((cch ^ (ra & 7))) << 3)];
#pragma unroll
      for (int ni = 0; ni < 4; ++ni) {
        int rb = ni * 16 + (lane & 15);
        half8 bf = *(const half8*)&lB[rb * BK + (((cch ^ (rb & 7))) << 3)];
        acc[ni] = __builtin_amdgcn_mfma_f32_16x16x32_f16(af, bf, acc[ni], 0, 0, 0);
      }
    }
    __syncthreads();
  }

  const int h = hc0 + (lane & 15);
  const float bi = gbias[h];
  const float bf_ = gbias[h + 512];
  const float bg = gbias[h + 1024];
  const float bo = gbias[h + 1536];
#pragma unroll
  for (int j = 0; j < 4; ++j) {
    long b = bm0 + w * 16 + (lane >> 4) * 4 + j;
    long idx = b * 512 + h;
    float iv = sigm(acc[0][j] + bi);
    float fv = sigm(acc[1][j] + bf_);
    float gv = tanh_f(acc[2][j] + bg);
    float ov = sigm(acc[3][j] + bo);
    float cc = fv * c[idx] + iv * gv;
    c[idx] = cc;
    float hh = ov * tanh_f(cc);
    _Float16 hf = (_Float16)hh;
    Anext[b * 1024 + 512 + h] = hf;
    hchunk[(long)tloc * (Bb * Hh) + idx] = hf;
    if (znext) Anext[b * 1024 + h] = (_Float16)(conds[idx] + znext[idx]);
  }
}

}  // namespace

extern "C" void kernel_launch(void* const* d_in, const int* in_sizes, int n_in,
                              void* d_out, int out_size, void* d_ws, size_t ws_size,
                              hipStream_t stream) {
  const float* labels = (const float*)d_in[0];
  const float* z      = (const float*)d_in[1];
  const float* W1     = (const float*)d_in[2];
  const float* b1     = (const float*)d_in[3];
  const float* W2     = (const float*)d_in[4];
  const float* b2     = (const float*)d_in[5];
  const float* W3     = (const float*)d_in[6];
  const float* Wih    = (const float*)d_in[7];
  const float* Whh    = (const float*)d_in[8];
  const float* bih    = (const float*)d_in[9];
  const float* bhh    = (const float*)d_in[10];
  const float* P1     = (const float*)d_in[11];
  const float* pb1    = (const float*)d_in[12];
  const float* P2     = (const float*)d_in[13];
  const float* pb2    = (const float*)d_in[14];
  const float* P3     = (const float*)d_in[15];
  const float* pb3    = (const float*)d_in[16];
  float* out = (float*)d_out;
  (void)in_sizes; (void)n_in; (void)out_size; (void)ws_size;

  char* p = (char*)d_ws;
  auto alloc = [&](size_t bytes) -> char* {
    char* r = p;
    p += (bytes + 255) & ~(size_t)255;
    return r;
  };
  _Float16* Wcat  = (_Float16*)alloc((size_t)Gg * 1024 * 2);   // 4 MB
  _Float16* P1h   = (_Float16*)alloc((size_t)Hh * Hh * 2);
  _Float16* P2h   = (_Float16*)alloc((size_t)Hh * Hh * 2);
  _Float16* P3h   = (_Float16*)alloc((size_t)Dd * Hh * 2);
  _Float16* W2h   = (_Float16*)alloc((size_t)Hh * Hh * 2);
  _Float16* W3h   = (_Float16*)alloc((size_t)Hh * Hh * 2);
  float*    gb    = (float*)alloc((size_t)Gg * 4);
  _Float16* x1    = (_Float16*)alloc((size_t)Bb * Hh * 2);
  _Float16* x2    = (_Float16*)alloc((size_t)Bb * Hh * 2);
  float*    conds = (float*)alloc((size_t)Bb * Hh * 4);
  float*    cbuf  = (float*)alloc((size_t)Bb * Hh * 4);
  _Float16* A0    = (_Float16*)alloc((size_t)Bb * 1024 * 2);
  _Float16* A1    = (_Float16*)alloc((size_t)Bb * 1024 * 2);
  _Float16* hch   = (_Float16*)alloc((size_t)CH * Bb * Hh * 2); // 16 MB
  _Float16* Y1    = (_Float16*)alloc((size_t)CH * Bb * Hh * 2); // 16 MB
  _Float16* Y2    = (_Float16*)alloc((size_t)CH * Bb * Hh * 2); // 16 MB
  // total ~ 65 MB of d_ws

  dim3 blk(256);

  // --- prep ---
  k_wcat<<<(Gg * 1024) / 256, blk, 0, stream>>>(Wih, Whh, Wcat);
  k_cvt<<<(Hh * Hh) / 256, blk, 0, stream>>>(P1, P1h, Hh * Hh);
  k_cvt<<<(Hh * Hh) / 256, blk, 0, stream>>>(P2, P2h, Hh * Hh);
  k_cvt<<<(Dd * Hh) / 256, blk, 0, stream>>>(P3, P3h, Dd * Hh);
  k_cvt<<<(Hh * Hh) / 256, blk, 0, stream>>>(W2, W2h, Hh * Hh);
  k_cvt<<<(Hh * Hh) / 256, blk, 0, stream>>>(W3, W3h, Hh * Hh);
  k_gbias<<<Gg / 256, blk, 0, stream>>>(bih, bhh, gb);

  // --- label MLP -> conds (f32) ---
  k_label1<<<(Bb * Hh) / 256, blk, 0, stream>>>(labels, W1, b1, x1);
  gemm_tn<64, 64><<<dim3(Bb / 64, Hh / 64), blk, 0, stream>>>(
      x1, Hh, W2h, Hh, b2, nullptr, x2, Hh, Hh, 1, 0, 0);
  gemm_tn<64, 64><<<dim3(Bb / 64, Hh / 64), blk, 0, stream>>>(
      x2, Hh, W3h, Hh, nullptr, conds, nullptr, Hh, Hh, 0, 0, 0);

  k_init<<<(Bb * Hh) / 256, blk, 0, stream>>>(cbuf, A0, conds, z);

  // --- recurrence + chunked proj ---
  for (int t = 0; t < Tt; ++t) {
    const _Float16* Acur = (t & 1) ? A1 : A0;
    _Float16* Anext = (t & 1) ? A0 : A1;
    const float* znext = (t + 1 < Tt) ? (z + (size_t)(t + 1) * Bb * Hh) : nullptr;
    step_fused<<<dim3(Bb / 64, Hh / 16), blk, 0, stream>>>(
        Acur, Wcat, gb, cbuf, Anext, hch, conds, znext, t & (CH - 1));
    if ((t & (CH - 1)) == (CH - 1)) {
      int t0 = t - (CH - 1);
      gemm_tn<128, 128><<<dim3(CH * Bb / 128, Hh / 128), blk, 0, stream>>>(
          hch, Hh, P1h, Hh, pb1, nullptr, Y1, Hh, Hh, 1, 0, 0);
      gemm_tn<128, 128><<<dim3(CH * Bb / 128, Hh / 128), blk, 0, stream>>>(
          Y1, Hh, P2h, Hh, pb2, nullptr, Y2, Hh, Hh, 1, 0, 0);
      gemm_tn<64, 64><<<dim3(CH * Bb / 64, Dd / 64), blk, 0, stream>>>(
          Y2, Hh, P3h, Hh, pb3, out, nullptr, Dd, Hh, 0, 1, t0);
    }
  }
}